// Round 12
// baseline (309.638 us; speedup 1.0000x reference)
//
#include <hip/hip_runtime.h>
#include <cmath>

#define NB 64
#define NN 16800
#define KK 1024
#define NT 1024
#define CAP 2048
#define RQ 17  // ceil(NN/NT)

typedef unsigned long long ull;

// Key (R13): fp32 conf bits, order-isomorphic to the double-sigmoid key
// (sigmoid strictly monotone; ties iff bit-equal cf; s>=0.5 <=> cf>=0
// exactly in both precisions). key = (bits&0x7FFFFFFF)+1 for cf>=0, else 0.
__device__ __forceinline__ unsigned int score_key_f(float cf) {
  if (!(cf >= 0.0f)) return 0u;
  return (__float_as_uint(cf) & 0x7FFFFFFFu) + 1u;
}

// Monotone exact bin: floor(cf*1024) clamped (power-of-2 scale, no rounding).
__device__ __forceinline__ unsigned int bin_of_key(unsigned int key) {
  float cf = __uint_as_float(key - 1u);  // key>=1: magnitude bits of cf
  unsigned int bi = (unsigned int)(int)(cf * 1024.0f);
  return bi > 4095u ? 4095u : bi;
}

// Shared double box decode (contract off => one codegen, numpy op order).
__device__ __forceinline__ void decode_box_d(const float* lp, const float* ap,
                                             double& X0, double& Y0,
                                             double& X1, double& Y1,
                                             double& AR) {
#pragma clang fp contract(off)
  double l0 = (double)lp[0], l1 = (double)lp[1];
  double l2 = (double)lp[2], l3 = (double)lp[3];
  double a0 = (double)ap[0], a1 = (double)ap[1];
  double a2 = (double)ap[2], a3 = (double)ap[3];
  double xy0 = a0 + (l0 * 0.1) * a2;
  double xy1 = a1 + (l1 * 0.1) * a3;
  double w = a2 * exp(l2 * 0.2);
  double h = a3 * exp(l3 * 0.2);
  X0 = xy0 - w * 0.5; Y0 = xy1 - h * 0.5;
  X1 = xy0 + w * 0.5; Y1 = xy1 + h * 0.5;
  AR = fmax(X1 - X0, 0.0) * fmax(Y1 - Y0, 0.0);
}

__device__ __forceinline__ bool iou_gt_d(double i0, double i1, double i2,
                                         double i3, double ia, double j0,
                                         double j1, double j2, double j3,
                                         double ja) {
#pragma clang fp contract(off)
  double lt0 = fmax(i0, j0), lt1 = fmax(i1, j1);
  double rb0 = fmin(i2, j2), rb1 = fmin(i3, j3);
  double w0 = fmax(rb0 - lt0, 0.0), w1 = fmax(rb1 - lt1, 0.0);
  double inter = w0 * w1;
  double den = ((ia + ja) - inter) + 1e-9;  // ref op order
  return (inter / den) > 0.3;
}

// ---- R21 monolithic: fast counting sort + in-LDS NMS, one block/image ----
// sort phase = sort_kernel's verified fast path (fp32 keys); NMS + output =
// fallback_kernel's verified body (R4, harness-passed). Boxes/scores/masks
// never leave LDS: eliminates 2 kernel launches, the 8MB mask round trip,
// and the fbox/sval/sidx round trips. LDS union: phase1 hist[4096]+
// base[4096] (32K) overlays phase2 fb0..fb3,farr (20K)+chunkmask (4K);
// phases separated by the existing cleanup-end barrier. Total ~54KB.
__global__ __launch_bounds__(1024, 1) void mono_kernel(
    const float* __restrict__ p_loc, const float* __restrict__ p_conf,
    const float* __restrict__ p_landms, const float* __restrict__ anchors,
    float* __restrict__ out) {
  const int b = blockIdx.x;
  const int tid = threadIdx.x;
  const int lane = tid & 63;
  const int wave = tid >> 6;

  __shared__ unsigned int skey[CAP];   // 8 KB
  __shared__ unsigned int sidx[CAP];   // 8 KB
  __shared__ char uni[32768];          // 32 KB union (see header comment)
  __shared__ float svalf[KK];          // 4 KB
  __shared__ unsigned int totals[64], chcarry[64];
  __shared__ unsigned int keepm[32];
  __shared__ ull supShared[16];
  __shared__ unsigned int sh_found, sh_binT, sh_cB;
  __shared__ unsigned int scnt, sh_digit, sh_r, sh_c;

  unsigned int* hist = reinterpret_cast<unsigned int*>(uni);          // 16 KB
  unsigned int* base = reinterpret_cast<unsigned int*>(uni + 16384);  // 16 KB
  float* fb0 = reinterpret_cast<float*>(uni);            // 4 KB (phase 2)
  float* fb1 = reinterpret_cast<float*>(uni + 4096);
  float* fb2 = reinterpret_cast<float*>(uni + 8192);
  float* fb3 = reinterpret_cast<float*>(uni + 12288);
  float* farr = reinterpret_cast<float*>(uni + 16384);
  ull (*chunkmask)[16] = reinterpret_cast<ull (*)[16]>(uni + 20480);  // 4 KB

  const float* conf = p_conf + (size_t)b * NN;

  // ---------- keys in registers ----------
  unsigned int rkey[RQ];
  #pragma unroll
  for (int q = 0; q < RQ; ++q) {
    const int i = tid + q * NT;
    rkey[q] = (i < NN) ? score_key_f(conf[i]) : 0u;
  }

  // ---------- FAST PATH: 12-bit counting sort (verbatim) ----------
  for (int i = tid; i < 4096; i += NT) hist[i] = 0u;
  if (tid == 0) sh_found = 0u;
  __syncthreads();
  #pragma unroll
  for (int q = 0; q < RQ; ++q) {
    unsigned int k = rkey[q];
    if (k != 0u) atomicAdd(&hist[bin_of_key(k)], 1u);
  }
  __syncthreads();
  // pass1: within-chunk inclusive scans from the high end (lane0 = high bin)
  for (int chunk = wave; chunk < 64; chunk += 16) {
    const int bin = chunk * 64 + (63 - lane);
    unsigned int c0 = hist[bin];
    unsigned int x = c0;
    #pragma unroll
    for (int d = 1; d < 64; d <<= 1) {
      unsigned int y = __shfl_up(x, d);
      if (lane >= d) x += y;
    }
    base[bin] = x;  // inclusive count of bins >= bin within chunk
    if (lane == 63) totals[chunk] = x;
  }
  __syncthreads();
  // chunk-level exclusive suffix (sum of strictly higher chunks)
  if (wave == 0) {
    const int chunk = 63 - lane;  // lane0 = highest chunk
    unsigned int t0 = totals[chunk];
    unsigned int x = t0;
    #pragma unroll
    for (int d = 1; d < 64; d <<= 1) {
      unsigned int y = __shfl_up(x, d);
      if (lane >= d) x += y;
    }
    chcarry[chunk] = x - t0;
  }
  __syncthreads();
  // pass2: finalize exact base ranks, detect the rank-1024 crossing bin
  for (int chunk = wave; chunk < 64; chunk += 16) {
    const int bin = chunk * 64 + (63 - lane);
    unsigned int c0 = hist[bin];
    unsigned int S = chcarry[chunk] + base[bin] - c0;  // strictly-higher total
    base[bin] = S;
    if (S < (unsigned)KK && (unsigned)KK <= S + c0) {
      sh_found = 1u; sh_binT = (unsigned int)bin; sh_cB = c0;
    }
  }
  __syncthreads();
  const bool fastOK = (sh_found != 0u) && (sh_cB <= 64u);
  const unsigned int binT = sh_binT;

  if (fastOK) {
    for (int i = tid; i < KK + 64; i += NT) { skey[i] = 0u; sidx[i] = 0xFFFFFFFFu; }
    __syncthreads();
    // scatter: candidates in bins >= binT land at exact rank + arrival offset
    #pragma unroll
    for (int q = 0; q < RQ; ++q) {
      const int i = tid + q * NT;
      unsigned int k = rkey[q];
      if (k != 0u) {
        unsigned int bin = bin_of_key(k);
        if (bin >= binT) {
          unsigned int pos = atomicAdd(&base[bin], 1u);
          if (pos < (unsigned)(KK + 64)) { skey[pos] = k; sidx[pos] = (unsigned int)i; }
        }
      }
    }
    __syncthreads();
    // in-bin cleanup: sort each bin slice by (key desc, idx asc); disjoint
    for (int bin = (int)binT + tid; bin < 4096; bin += NT) {
      unsigned int cnt = hist[bin];
      if (cnt >= 2u) {
        int hi2 = (int)base[bin];       // orig + cnt after scatter
        int lo2 = hi2 - (int)cnt;
        for (int m2 = lo2 + 1; m2 < hi2; ++m2) {
          unsigned int kx = skey[m2]; unsigned int ix = sidx[m2];
          int n2 = m2;
          while (n2 > lo2) {
            unsigned int kp = skey[n2 - 1]; unsigned int ip = sidx[n2 - 1];
            bool after = (kp < kx) || (kp == kx && ip > ix);
            if (!after) break;
            skey[n2] = kp; sidx[n2] = ip; --n2;
          }
          skey[n2] = kx; sidx[n2] = ix;
        }
      }
    }
    __syncthreads();
  } else {
    // ---------- FALLBACK: radix-select (32-bit) + bitonic-2048 ----------
    unsigned int r = KK;
    unsigned int prefix = 0u, T = 0u;
    for (int pass = 0; pass < 4; ++pass) {
      const int shift = 24 - pass * 8;
      if (tid < 256) hist[tid] = 0u;
      __syncthreads();
      const unsigned int pm = pass ? ~((1u << (shift + 8)) - 1u) : 0u;
      #pragma unroll
      for (int q = 0; q < RQ; ++q) {
        unsigned int k = rkey[q];
        if (k != 0u && (k & pm) == prefix)
          atomicAdd(&hist[(k >> shift) & 255u], 1u);
      }
      __syncthreads();
      if (wave == 0) {
        if (lane == 0) { sh_digit = 0u; sh_r = r; sh_c = 0u; }
        unsigned int carry = 0;
        for (int chunk = 3; chunk >= 0; --chunk) {
          const int bin = chunk * 64 + (63 - lane);
          unsigned int c = hist[bin];
          unsigned int x = c;
          #pragma unroll
          for (int d = 1; d < 64; d <<= 1) {
            unsigned int y = __shfl_up(x, d);
            if (lane >= d) x += y;
          }
          unsigned int excl = x - c;
          unsigned int S = carry + excl;
          bool hit = (S < r) && (r <= S + c);
          ull bal = __ballot(hit ? 1 : 0);
          if (bal != 0ull) {
            int hl = __ffsll((long long)bal) - 1;
            unsigned int Sf = __shfl(S, hl);
            unsigned int bf = __shfl((unsigned int)bin, hl);
            unsigned int cf2 = __shfl(c, hl);
            if (lane == 0) { sh_digit = bf; sh_r = r - Sf; sh_c = cf2; }
            break;
          }
          carry += __shfl(x, 63);
        }
      }
      __syncthreads();
      prefix |= (sh_digit << shift);
      r = sh_r;
      const unsigned int cntge = (KK - r) + sh_c;
      if (cntge <= CAP || pass == 3) { T = prefix; break; }
    }

    if (tid == 0) scnt = 0u;
    for (int i = tid; i < CAP; i += NT) { skey[i] = 0u; sidx[i] = 0xFFFFFFFFu; }
    __syncthreads();
    #pragma unroll
    for (int q = 0; q < RQ; ++q) {
      const int i = tid + q * NT;
      unsigned int k = rkey[q];
      if (k != 0u && k >= T) {
        unsigned int pos = atomicAdd(&scnt, 1u);
        if (pos < CAP) { skey[pos] = k; sidx[pos] = (unsigned int)i; }
      }
    }
    __syncthreads();

    for (unsigned int k2 = 2; k2 <= CAP; k2 <<= 1) {
      for (unsigned int j = k2 >> 1; j > 0; j >>= 1) {
        for (int i = tid; i < CAP; i += NT) {
          int ixj = i ^ (int)j;
          if (ixj > i) {
            bool up = ((i & k2) == 0);
            unsigned int ka = skey[i], kbv = skey[ixj];
            unsigned int ia = sidx[i], ib = sidx[ixj];
            bool a_after_b = (ka < kbv) || (ka == kbv && ia > ib);
            if (a_after_b == up) {
              skey[i] = kbv; skey[ixj] = ka;
              sidx[i] = ib; sidx[ixj] = ia;
            }
          }
        }
        __syncthreads();
      }
    }
  }

  // ---------- decode top-K in double -> LDS (fallback style) --------------
  // hist/base are DEAD from here (cleanup ended with a barrier); fb*/farr
  // overlay them. Column doubles kept in registers for the rare path.
  const unsigned int mykey = skey[tid];
  const unsigned int myidx = sidx[tid];
  double dX0 = 0.0, dY0 = 0.0, dX1 = 0.0, dY1 = 0.0, dAR = 0.0;
  {
    float v = -1.0f;
    if (mykey != 0u) {
      decode_box_d(p_loc + ((size_t)b * NN + myidx) * 4,
                   anchors + (size_t)myidx * 4, dX0, dY0, dX1, dY1, dAR);
      double s = 1.0 / (1.0 + exp(-(double)conf[myidx]));
      v = (float)s;
    }
    fb0[tid] = (float)dX0; fb1[tid] = (float)dY0;
    fb2[tid] = (float)dX1; fb3[tid] = (float)dY1;
    farr[tid] = (float)dAR;
    svalf[tid] = v;
  }
  if (tid < 16) supShared[tid] = 0ull;
  if (tid < 32) keepm[tid] = 0u;
  __syncthreads();

  // ---------- NMS (verbatim fallback_kernel body) --------------------------
  const float cj0 = fb0[tid], cj1 = fb1[tid], cj2 = fb2[tid], cj3 = fb3[tid];
  const float caj = farr[tid];
  ull supw = 0ull;

  for (int c = 0; c < 32; ++c) {
    for (int rr = 0; rr < 32; ++rr) {
      const int i = c * 32 + rr;
      const bool rowDead =
          (svalf[i] < 0.0f) ||
          (((supShared[i >> 6] >> (i & 63)) & 1ull) != 0ull);
      if (rowDead) continue;
      float bi0 = fb0[i], bi1 = fb1[i], bi2 = fb2[i], bi3 = fb3[i];
      float ai = farr[i];
      float lt0 = fmaxf(bi0, cj0), lt1 = fmaxf(bi1, cj1);
      float q0 = fminf(bi2, cj2), q1 = fminf(bi3, cj3);
      float w0 = fmaxf(q0 - lt0, 0.0f), w1 = fmaxf(q1 - lt1, 0.0f);
      float inter = w0 * w1;
      float den = ((ai + caj) - inter) + 1e-9f;
      float d = inter - 0.3f * den;
      bool bit = d > 0.0f;
      bool unc = fabsf(d) <= den * 1e-3f;
      if (__builtin_expect((bool)__ballot(unc ? 1 : 0), 0)) {
        if (unc) {
          const unsigned int ridx = sidx[i];
          double rX0, rY0, rX1, rY1, rAR;
          decode_box_d(p_loc + ((size_t)b * NN + ridx) * 4,
                       anchors + (size_t)ridx * 4, rX0, rY0, rX1, rY1, rAR);
          bit = iou_gt_d(rX0, rY0, rX1, rY1, rAR, dX0, dY0, dX1, dY1, dAR);
        }
      }
      bit = bit && (tid > i);
      ull m = __ballot(bit ? 1 : 0);
      if (lane == 0) chunkmask[rr][wave] = m;
    }
    __syncthreads();
    if (wave == 0) {
      unsigned int km = 0u;
      for (int rr = 0; rr < 32; ++rr) {
        const int i = c * 32 + rr;
        ull sc = __shfl(supw, i >> 6);
        bool keep = (svalf[i] >= 0.0f) && (((sc >> (i & 63)) & 1ull) == 0ull);
        if (keep) {
          km |= (1u << rr);
          if (lane < 16) supw |= chunkmask[rr][lane];
        }
      }
      if (lane == 0) keepm[c] = km;
      if (lane < 16) supShared[lane] = supw;
    }
    __syncthreads();
  }

  // ---------- output (verbatim fallback_kernel epilogue) -------------------
  {
    const bool keep = ((keepm[tid >> 5] >> (tid & 31)) & 1u) != 0u;
    float* op = out + ((size_t)b * KK + tid) * 15;
    if (keep) {
      op[0] = fb0[tid]; op[1] = fb1[tid]; op[2] = fb2[tid]; op[3] = fb3[tid];
      const float* pp = p_landms + ((size_t)b * NN + myidx) * 10;
      const float* ap = anchors + (size_t)myidx * 4;
      double a0 = (double)ap[0], a1 = (double)ap[1];
      double a2 = (double)ap[2], a3 = (double)ap[3];
      #pragma unroll
      for (int q = 0; q < 5; ++q) {
        double px = (double)pp[2 * q], py = (double)pp[2 * q + 1];
        op[4 + 2 * q]     = (float)(a0 + (px * 0.1) * a2);
        op[4 + 2 * q + 1] = (float)(a1 + (py * 0.1) * a3);
      }
      op[14] = svalf[tid];
    } else {
      #pragma unroll
      for (int q = 0; q < 15; ++q) op[q] = 0.0f;
    }
  }
}

extern "C" void kernel_launch(void* const* d_in, const int* in_sizes, int n_in,
                              void* d_out, int out_size, void* d_ws, size_t ws_size,
                              hipStream_t stream) {
  const float* p_loc    = (const float*)d_in[0];
  const float* p_conf   = (const float*)d_in[1];
  const float* p_landms = (const float*)d_in[2];
  const float* anchors  = (const float*)d_in[3];
  float* out = (float*)d_out;
  (void)in_sizes; (void)n_in; (void)out_size; (void)d_ws; (void)ws_size;

  // R21: single monolithic kernel, no workspace required.
  hipLaunchKernelGGL(mono_kernel, dim3(NB), dim3(NT), 0, stream,
                     p_loc, p_conf, p_landms, anchors, out);
}

// Round 13
// 200.613 us; speedup vs baseline: 1.5435x; 1.5435x over previous
//
#include <hip/hip_runtime.h>
#include <cmath>

#define NB 64
#define NN 16800
#define KK 1024
#define NT 1024
#define CAP 2048
#define RQ 17  // ceil(NN/NT)

typedef unsigned long long ull;

// Key (R13): fp32 conf bits, order-isomorphic to the double-sigmoid key
// (sigmoid strictly monotone; ties iff bit-equal cf; s>=0.5 <=> cf>=0
// exactly in both precisions). key = (bits&0x7FFFFFFF)+1 for cf>=0, else 0.
__device__ __forceinline__ unsigned int score_key_f(float cf) {
  if (!(cf >= 0.0f)) return 0u;
  return (__float_as_uint(cf) & 0x7FFFFFFFu) + 1u;
}

// Monotone exact bin: floor(cf*1024) clamped (power-of-2 scale, no rounding).
__device__ __forceinline__ unsigned int bin_of_key(unsigned int key) {
  float cf = __uint_as_float(key - 1u);  // key>=1: magnitude bits of cf
  unsigned int bi = (unsigned int)(int)(cf * 1024.0f);
  return bi > 4095u ? 4095u : bi;
}

// Legacy double key (fallback_kernel only).
__device__ __forceinline__ ull score_key_d(float cf) {
  double s = 1.0 / (1.0 + exp(-(double)cf));
  if (!(s >= 0.5)) return 0ull;
  return ((ull)__double_as_longlong(s) & 0xFFFFFFFFFFFFFull) + 1ull;
}

// Shared double box decode (contract off => one codegen, numpy op order).
__device__ __forceinline__ void decode_box_d(const float* lp, const float* ap,
                                             double& X0, double& Y0,
                                             double& X1, double& Y1,
                                             double& AR) {
#pragma clang fp contract(off)
  double l0 = (double)lp[0], l1 = (double)lp[1];
  double l2 = (double)lp[2], l3 = (double)lp[3];
  double a0 = (double)ap[0], a1 = (double)ap[1];
  double a2 = (double)ap[2], a3 = (double)ap[3];
  double xy0 = a0 + (l0 * 0.1) * a2;
  double xy1 = a1 + (l1 * 0.1) * a3;
  double w = a2 * exp(l2 * 0.2);
  double h = a3 * exp(l3 * 0.2);
  X0 = xy0 - w * 0.5; Y0 = xy1 - h * 0.5;
  X1 = xy0 + w * 0.5; Y1 = xy1 + h * 0.5;
  AR = fmax(X1 - X0, 0.0) * fmax(Y1 - Y0, 0.0);
}

__device__ __forceinline__ bool iou_gt_d(double i0, double i1, double i2,
                                         double i3, double ia, double j0,
                                         double j1, double j2, double j3,
                                         double ja) {
#pragma clang fp contract(off)
  double lt0 = fmax(i0, j0), lt1 = fmax(i1, j1);
  double rb0 = fmin(i2, j2), rb1 = fmin(i3, j3);
  double w0 = fmax(rb0 - lt0, 0.0), w1 = fmax(rb1 - lt1, 0.0);
  double inter = w0 * w1;
  double den = ((ia + ja) - inter) + 1e-9;  // ref op order
  return (inter / den) > 0.3;
}

// 64-bit readlane: 2x v_readlane_b32 -> SGPR pair (fast, no LDS pipe)
__device__ __forceinline__ ull readlane64(ull v, int l) {
  unsigned int lo = __builtin_amdgcn_readlane((unsigned int)v, l);
  unsigned int hi = __builtin_amdgcn_readlane((unsigned int)(v >> 32), l);
  return ((ull)hi << 32) | (ull)lo;
}

// 64-bit shuffle (2x ds_bpermute via __shfl)
__device__ __forceinline__ ull shfl64(ull v, int src) {
  unsigned int lo = (unsigned int)__shfl((int)(unsigned int)v, src);
  unsigned int hi = (unsigned int)__shfl((int)(unsigned int)(v >> 32), src);
  return ((ull)hi << 32) | (ull)lo;
}

__device__ __forceinline__ ull shflxor64(ull v, int m) {
  unsigned int lo = (unsigned int)__shfl_xor((int)(unsigned int)v, m);
  unsigned int hi = (unsigned int)__shfl_xor((int)(unsigned int)(v >> 32), m);
  return ((ull)hi << 32) | (ull)lo;
}

// ---- K2: per-image exact counting sort, fp32-bit keys in-register ---------
__global__ __launch_bounds__(1024, 1) void sort_kernel(
    const float* __restrict__ p_loc, const float* __restrict__ p_conf,
    const float* __restrict__ anchors, unsigned int* __restrict__ sidx_s,
    float* __restrict__ fbox, float* __restrict__ sval) {
  const int b = blockIdx.x;
  const int tid = threadIdx.x;
  const int lane = tid & 63;
  const int wave = tid >> 6;

  __shared__ unsigned int skey[CAP];   // 8 KB
  __shared__ unsigned int sidx[CAP];   // 8 KB
  __shared__ unsigned int hist[4096];  // 16 KB ([0..256) reused by fallback)
  __shared__ unsigned int base[4096];  // 16 KB
  __shared__ unsigned int totals[64], chcarry[64];
  __shared__ unsigned int sh_found, sh_binT, sh_cB;
  __shared__ unsigned int scnt, sh_digit, sh_r, sh_c;

  const float* conf = p_conf + (size_t)b * NN;

  // ---------- keys in registers ----------
  unsigned int rkey[RQ];
  #pragma unroll
  for (int q = 0; q < RQ; ++q) {
    const int i = tid + q * NT;
    rkey[q] = (i < NN) ? score_key_f(conf[i]) : 0u;
  }

  // ---------- FAST PATH: 12-bit counting sort ----------
  for (int i = tid; i < 4096; i += NT) hist[i] = 0u;
  if (tid == 0) sh_found = 0u;
  __syncthreads();
  #pragma unroll
  for (int q = 0; q < RQ; ++q) {
    unsigned int k = rkey[q];
    if (k != 0u) atomicAdd(&hist[bin_of_key(k)], 1u);
  }
  __syncthreads();
  // pass1: within-chunk inclusive scans from the high end (lane0 = high bin)
  for (int chunk = wave; chunk < 64; chunk += 16) {
    const int bin = chunk * 64 + (63 - lane);
    unsigned int c0 = hist[bin];
    unsigned int x = c0;
    #pragma unroll
    for (int d = 1; d < 64; d <<= 1) {
      unsigned int y = __shfl_up(x, d);
      if (lane >= d) x += y;
    }
    base[bin] = x;  // inclusive count of bins >= bin within chunk
    if (lane == 63) totals[chunk] = x;
  }
  __syncthreads();
  // chunk-level exclusive suffix (sum of strictly higher chunks)
  if (wave == 0) {
    const int chunk = 63 - lane;  // lane0 = highest chunk
    unsigned int t0 = totals[chunk];
    unsigned int x = t0;
    #pragma unroll
    for (int d = 1; d < 64; d <<= 1) {
      unsigned int y = __shfl_up(x, d);
      if (lane >= d) x += y;
    }
    chcarry[chunk] = x - t0;
  }
  __syncthreads();
  // pass2: finalize exact base ranks, detect the rank-1024 crossing bin
  for (int chunk = wave; chunk < 64; chunk += 16) {
    const int bin = chunk * 64 + (63 - lane);
    unsigned int c0 = hist[bin];
    unsigned int S = chcarry[chunk] + base[bin] - c0;  // strictly-higher total
    base[bin] = S;
    if (S < (unsigned)KK && (unsigned)KK <= S + c0) {
      sh_found = 1u; sh_binT = (unsigned int)bin; sh_cB = c0;
    }
  }
  __syncthreads();
  const bool fastOK = (sh_found != 0u) && (sh_cB <= 64u);
  const unsigned int binT = sh_binT;

  if (fastOK) {
    for (int i = tid; i < KK + 64; i += NT) { skey[i] = 0u; sidx[i] = 0xFFFFFFFFu; }
    __syncthreads();
    // scatter: candidates in bins >= binT land at exact rank + arrival offset
    #pragma unroll
    for (int q = 0; q < RQ; ++q) {
      const int i = tid + q * NT;
      unsigned int k = rkey[q];
      if (k != 0u) {
        unsigned int bin = bin_of_key(k);
        if (bin >= binT) {
          unsigned int pos = atomicAdd(&base[bin], 1u);
          if (pos < (unsigned)(KK + 64)) { skey[pos] = k; sidx[pos] = (unsigned int)i; }
        }
      }
    }
    __syncthreads();
    // in-bin cleanup: sort each bin slice by (key desc, idx asc); disjoint
    for (int bin = (int)binT + tid; bin < 4096; bin += NT) {
      unsigned int cnt = hist[bin];
      if (cnt >= 2u) {
        int hi2 = (int)base[bin];       // orig + cnt after scatter
        int lo2 = hi2 - (int)cnt;
        for (int m2 = lo2 + 1; m2 < hi2; ++m2) {
          unsigned int kx = skey[m2]; unsigned int ix = sidx[m2];
          int n2 = m2;
          while (n2 > lo2) {
            unsigned int kp = skey[n2 - 1]; unsigned int ip = sidx[n2 - 1];
            bool after = (kp < kx) || (kp == kx && ip > ix);
            if (!after) break;
            skey[n2] = kp; sidx[n2] = ip; --n2;
          }
          skey[n2] = kx; sidx[n2] = ix;
        }
      }
    }
    __syncthreads();
  } else {
    // ---------- FALLBACK: radix-select (32-bit) + bitonic-2048 ----------
    unsigned int r = KK;
    unsigned int prefix = 0u, T = 0u;
    for (int pass = 0; pass < 4; ++pass) {
      const int shift = 24 - pass * 8;
      if (tid < 256) hist[tid] = 0u;
      __syncthreads();
      const unsigned int pm = pass ? ~((1u << (shift + 8)) - 1u) : 0u;
      #pragma unroll
      for (int q = 0; q < RQ; ++q) {
        unsigned int k = rkey[q];
        if (k != 0u && (k & pm) == prefix)
          atomicAdd(&hist[(k >> shift) & 255u], 1u);
      }
      __syncthreads();
      if (wave == 0) {
        if (lane == 0) { sh_digit = 0u; sh_r = r; sh_c = 0u; }
        unsigned int carry = 0;
        for (int chunk = 3; chunk >= 0; --chunk) {
          const int bin = chunk * 64 + (63 - lane);
          unsigned int c = hist[bin];
          unsigned int x = c;
          #pragma unroll
          for (int d = 1; d < 64; d <<= 1) {
            unsigned int y = __shfl_up(x, d);
            if (lane >= d) x += y;
          }
          unsigned int excl = x - c;
          unsigned int S = carry + excl;
          bool hit = (S < r) && (r <= S + c);
          ull bal = __ballot(hit ? 1 : 0);
          if (bal != 0ull) {
            int hl = __ffsll((long long)bal) - 1;
            unsigned int Sf = __shfl(S, hl);
            unsigned int bf = __shfl((unsigned int)bin, hl);
            unsigned int cf2 = __shfl(c, hl);
            if (lane == 0) { sh_digit = bf; sh_r = r - Sf; sh_c = cf2; }
            break;
          }
          carry += __shfl(x, 63);
        }
      }
      __syncthreads();
      prefix |= (sh_digit << shift);
      r = sh_r;
      const unsigned int cntge = (KK - r) + sh_c;
      if (cntge <= CAP || pass == 3) { T = prefix; break; }
    }

    if (tid == 0) scnt = 0u;
    for (int i = tid; i < CAP; i += NT) { skey[i] = 0u; sidx[i] = 0xFFFFFFFFu; }
    __syncthreads();
    #pragma unroll
    for (int q = 0; q < RQ; ++q) {
      const int i = tid + q * NT;
      unsigned int k = rkey[q];
      if (k != 0u && k >= T) {
        unsigned int pos = atomicAdd(&scnt, 1u);
        if (pos < CAP) { skey[pos] = k; sidx[pos] = (unsigned int)i; }
      }
    }
    __syncthreads();

    for (unsigned int k2 = 2; k2 <= CAP; k2 <<= 1) {
      for (unsigned int j = k2 >> 1; j > 0; j >>= 1) {
        for (int i = tid; i < CAP; i += NT) {
          int ixj = i ^ (int)j;
          if (ixj > i) {
            bool up = ((i & k2) == 0);
            unsigned int ka = skey[i], kbv = skey[ixj];
            unsigned int ia = sidx[i], ib = sidx[ixj];
            bool a_after_b = (ka < kbv) || (ka == kbv && ia > ib);
            if (a_after_b == up) {
              skey[i] = kbv; skey[ixj] = ka;
              sidx[i] = ib; sidx[ixj] = ia;
            }
          }
        }
        __syncthreads();
      }
    }
  }

  // ---------- decode top-K boxes in double, emit fp32 + idx + score --------
  const unsigned int mykey = skey[tid];
  const unsigned int myidx = sidx[tid];
  double X0 = 0.0, Y0 = 0.0, X1 = 0.0, Y1 = 0.0, AR = 0.0;
  float v = -1.0f;
  if (mykey != 0u) {
    decode_box_d(p_loc + ((size_t)b * NN + myidx) * 4,
                 anchors + (size_t)myidx * 4, X0, Y0, X1, Y1, AR);
    double s = 1.0 / (1.0 + exp(-(double)conf[myidx]));
    v = (float)s;
  }
  sidx_s[(size_t)b * KK + tid] = myidx;
  float* fb = fbox + (size_t)b * 5 * KK;
  fb[0 * KK + tid] = (float)X0; fb[1 * KK + tid] = (float)Y0;
  fb[2 * KK + tid] = (float)X1; fb[3 * KK + tid] = (float)Y1;
  fb[4 * KK + tid] = (float)AR;
  sval[(size_t)b * KK + tid] = v;
}

// ---- K3: triangle IoU bitmask, one (rowgroup,colgroup) task per wave ------
// grid = (64 img, 34); block = 256 (4 waves). Final form (best measured:
// 49.2-49.5 us): LDS same-address row broadcast, 8-row register chunks.
// Floor is ballot/exec-mask machinery (4 restructures converged to 49-51).
// Fusion architectures all measured >2x worse (R15/R17/R21): per-block
// device-scope coherence on 8 XCDs costs far more than kernel boundaries.
__global__ __launch_bounds__(256) void pair_kernel(
    const float* __restrict__ p_loc, const float* __restrict__ anchors,
    const unsigned int* __restrict__ sidx_s, const float* __restrict__ fbox,
    const float* __restrict__ sval, ull* __restrict__ maskg) {
  const int img = blockIdx.x;
  const int wave = threadIdx.x >> 6;
  const int lane = threadIdx.x & 63;
  const int t = blockIdx.y * 4 + wave;  // 0..135

  int rg = 0, rem = t;
  while (rem >= 16 - rg) { rem -= 16 - rg; ++rg; }
  const int cg = rg + rem;

  const int rgs = __builtin_amdgcn_readfirstlane(rg);  // uniform rg

  __shared__ float rowbuf[4][64][8];  // 8 KB; [wave] slices, wave-coherent

  const float* fb = fbox + (size_t)img * 5 * KK;
  const int irow = rgs * 64 + lane;
  const int jcol = cg * 64 + lane;

  // one-time stage: lane l loads row (rgs*64+l)'s box, writes its LDS row
  {
    const float v0 = fb[0 * KK + irow], v1 = fb[1 * KK + irow];
    const float v2 = fb[2 * KK + irow], v3 = fb[3 * KK + irow];
    const float va = fb[4 * KK + irow];
    float4* dst = reinterpret_cast<float4*>(&rowbuf[wave][lane][0]);
    *dst = make_float4(v0, v1, v2, v3);
    rowbuf[wave][lane][4] = va;
  }

  const unsigned int ri = sidx_s[(size_t)img * KK + irow];  // rare path only

  const float cj0 = fb[0 * KK + jcol], cj1 = fb[1 * KK + jcol];
  const float cj2 = fb[2 * KK + jcol], cj3 = fb[3 * KK + jcol];
  const float caj = fb[4 * KK + jcol];
  const unsigned int cidx = sidx_s[(size_t)img * KK + jcol];

  unsigned int wlo = 0u, whi = 0u;  // lane rr holds mask word for row rr

  for (int rc = 0; rc < 64; rc += 8) {
    // ---- chunk prefetch: 16 independent LDS broadcast reads ----
    float b0r[8], b1r[8], b2r[8], b3r[8], bar[8];
    #pragma unroll
    for (int u = 0; u < 8; ++u) {
      const float4 bq =
          *reinterpret_cast<const float4*>(&rowbuf[wave][rc + u][0]);
      b0r[u] = bq.x; b1r[u] = bq.y; b2r[u] = bq.z; b3r[u] = bq.w;
      bar[u] = rowbuf[wave][rc + u][4];
    }
    // ---- 8 row bodies from registers ----
    #pragma unroll
    for (int u = 0; u < 8; ++u) {
      const int rr = rc + u;
      const float bi0 = b0r[u], bi1 = b1r[u];
      const float bi2 = b2r[u], bi3 = b3r[u];
      const float ai = bar[u];
      float lt0 = fmaxf(bi0, cj0), lt1 = fmaxf(bi1, cj1);
      float q0 = fminf(bi2, cj2), q1 = fminf(bi3, cj3);
      float w0 = fmaxf(q0 - lt0, 0.0f), w1 = fmaxf(q1 - lt1, 0.0f);
      float inter = w0 * w1;
      float den = ((ai + caj) - inter) + 1e-9f;
      float d = inter - 0.3f * den;     // sign(d) = sign(iou - 0.3)
      bool bit = d > 0.0f;
      bool unc = fabsf(d) <= den * 1e-3f;  // fp32 iou err ~1e-5 << 1e-3
      if (__builtin_expect((bool)__ballot(unc ? 1 : 0), 0)) {
        const unsigned int rbi = __builtin_amdgcn_readlane(ri, rr);
        if (unc) {
          double rX0, rY0, rX1, rY1, rAR, qX0, qY0, qX1, qY1, qAR;
          decode_box_d(p_loc + ((size_t)img * NN + rbi) * 4,
                       anchors + (size_t)rbi * 4, rX0, rY0, rX1, rY1, rAR);
          decode_box_d(p_loc + ((size_t)img * NN + cidx) * 4,
                       anchors + (size_t)cidx * 4, qX0, qY0, qX1, qY1, qAR);
          bit = iou_gt_d(rX0, rY0, rX1, rY1, rAR, qX0, qY0, qX1, qY1, qAR);
        }
      }
      bit = bit && (jcol > rgs * 64 + rr);  // j > i
      ull m = __ballot(bit ? 1 : 0);
      const bool mine = (lane == rr);
      wlo = mine ? (unsigned int)m : wlo;
      whi = mine ? (unsigned int)(m >> 32) : whi;
    }
  }

  maskg[((size_t)img * KK + (size_t)rgs * 64 + lane) * 16 + cg] =
      ((ull)whi << 32) | (ull)wlo;
}

// ---- K4: serial resolve from bitmask + output -----------------------------
// R14 version (measured good): LDS/VALU off the serial chain; diag words
// preloaded vectorized; serial loop pure SALU; cross-word ORs deferred to
// one parallel pass per group (decision-identical).
__global__ __launch_bounds__(1024, 1) void resolve_kernel(
    const float* __restrict__ p_landms, const float* __restrict__ anchors,
    const unsigned int* __restrict__ sidx_s, const float* __restrict__ fbox,
    const float* __restrict__ sval, const ull* __restrict__ maskg,
    float* __restrict__ out) {
  const int img = blockIdx.x, tid = threadIdx.x, lane = tid & 63,
            wave = tid >> 6;
  __shared__ ull buf[2][2048];  // 2 x (128 rows x 16 words) = 32 KB
  __shared__ float svbuf[KK];
  __shared__ ull keepw[16];
  const ull* mg = maskg + (size_t)img * KK * 16;

  svbuf[tid] = sval[(size_t)img * KK + tid];
  for (int u = tid; u < 2048; u += NT) buf[0][u] = mg[u];
  __syncthreads();

  ull supw = 0ull;  // wave0: lane L<16 holds suppression word L
  for (int s = 0; s < 8; ++s) {
    const int cur = s & 1;
    if (wave != 0) {
      if (s + 1 < 8) {  // prefetch next 128 rows; only words >= 2(s+1) needed
        const ull* src = mg + (size_t)(s + 1) * 2048;
        const int wmin = 2 * (s + 1);
        for (int u = tid - 64; u < 2048; u += NT - 64)
          if ((u & 15) >= wmin) buf[cur ^ 1][u] = src[u];
      }
    } else {
      #pragma unroll
      for (int half = 0; half < 2; ++half) {
        const int g = 2 * s + half;  // global 64-row group
        const ull vm = __ballot(svbuf[g * 64 + lane] >= 0.0f);  // validity
        // (a) vectorized diag-word preload: lane rr <- row rr's word g
        const ull diagw = buf[cur][(half * 64 + lane) * 16 + g];
        // (b) serial scan: pure SALU chain
        ull curw = readlane64(supw, g);
        ull km = 0ull;
        #pragma unroll 8
        for (int rr = 0; rr < 64; ++rr) {
          const ull mw = readlane64(diagw, rr);  // indep of chain
          const ull bitm = 1ull << rr;
          const ull keepbit = (vm & ~curw) & bitm;
          km |= keepbit;
          curw |= (keepbit != 0ull) ? mw : 0ull;
        }
        if (lane == 0) keepw[g] = km;
        // (c) deferred cross-word OR: 4 lanes/word, 16 rows/lane
        if (g < 15) {
          const int w = lane >> 2, sub = lane & 3;
          ull acc = 0ull;
          #pragma unroll
          for (int t2 = 0; t2 < 16; ++t2) {
            const int rr = sub * 16 + t2;
            ull mv = buf[cur][(half * 64 + rr) * 16 + w];
            const ull kb = (km >> rr) & 1ull;
            acc |= (kb != 0ull) ? mv : 0ull;
          }
          if (w < g) acc = 0ull;  // words < g: garbage/unneeded
          acc |= shflxor64(acc, 1);
          acc |= shflxor64(acc, 2);
          const ull g4 = shfl64(acc, (lane & 15) * 4);
          if (lane < 16) supw |= g4;
          if (lane == g) supw = curw;  // exact diagonal word
        }
      }
    }
    __syncthreads();
  }

  const bool keep = ((keepw[tid >> 6] >> (tid & 63)) & 1ull) != 0ull;
  float* op = out + ((size_t)img * KK + tid) * 15;
  if (keep) {
    const float* fb = fbox + (size_t)img * 5 * KK;
    op[0] = fb[0 * KK + tid]; op[1] = fb[1 * KK + tid];
    op[2] = fb[2 * KK + tid]; op[3] = fb[3 * KK + tid];
    const unsigned int myidx = sidx_s[(size_t)img * KK + tid];
    const float* pp = p_landms + ((size_t)img * NN + myidx) * 10;
    const float* ap = anchors + (size_t)myidx * 4;
    double a0 = (double)ap[0], a1 = (double)ap[1];
    double a2 = (double)ap[2], a3 = (double)ap[3];
    #pragma unroll
    for (int q = 0; q < 5; ++q) {
      double px = (double)pp[2 * q], py = (double)pp[2 * q + 1];
      op[4 + 2 * q]     = (float)(a0 + (px * 0.1) * a2);
      op[4 + 2 * q + 1] = (float)(a1 + (py * 0.1) * a3);
    }
    op[14] = svbuf[tid];
  } else {
    #pragma unroll
    for (int q = 0; q < 15; ++q) op[q] = 0.0f;
  }
}

// ---- Fallback: R4 monolithic (passed; used only if ws too small) ----------
__global__ __launch_bounds__(1024, 1) void fallback_kernel(
    const float* __restrict__ p_loc, const float* __restrict__ p_conf,
    const float* __restrict__ p_landms, const float* __restrict__ anchors,
    const ull* __restrict__ gkeys, float* __restrict__ out) {
  const int b = blockIdx.x;
  const int tid = threadIdx.x;
  const int lane = tid & 63;
  const int wave = tid >> 6;

  __shared__ ull skey[CAP];
  __shared__ unsigned int sidx[CAP];
  __shared__ float fb0[KK], fb1[KK], fb2[KK], fb3[KK], farr[KK];
  __shared__ float svalf[KK];
  __shared__ ull chunkmask[32][16];
  __shared__ unsigned int keepm[32];
  __shared__ ull supShared[16];
  __shared__ unsigned int hist[256];
  __shared__ unsigned int scnt, sh_digit, sh_r;

  unsigned long long rkey[RQ];
  if (gkeys != nullptr) {
    const ull* kb = gkeys + (size_t)b * NN;
    #pragma unroll
    for (int q = 0; q < RQ; ++q) {
      const int i = tid + q * NT;
      rkey[q] = (i < NN) ? kb[i] : 0ull;
    }
  } else {
    const float* conf = p_conf + (size_t)b * NN;
    #pragma unroll
    for (int q = 0; q < RQ; ++q) {
      const int i = tid + q * NT;
      rkey[q] = (i < NN) ? score_key_d(conf[i]) : 0ull;
    }
  }

  unsigned int r = KK;
  ull prefix = 0ull;
  for (int pass = 0; pass < 7; ++pass) {
    const int shift = 48 - pass * 8;
    if (tid < 256) hist[tid] = 0u;
    __syncthreads();
    const ull pm = (pass == 0) ? 0ull : ~((1ull << (shift + 8)) - 1ull);
    #pragma unroll
    for (int q = 0; q < RQ; ++q) {
      const int i = tid + q * NT;
      if (i < NN) {
        ull k = rkey[q];
        if (k != 0ull && (k & pm) == prefix)
          atomicAdd(&hist[(unsigned int)(k >> shift) & 255u], 1u);
      }
    }
    __syncthreads();
    if (wave == 0) {
      if (lane == 0) { sh_digit = 0u; sh_r = r; }
      unsigned int carry = 0;
      for (int chunk = 3; chunk >= 0; --chunk) {
        const int bin = chunk * 64 + (63 - lane);
        unsigned int c = hist[bin];
        unsigned int x = c;
        #pragma unroll
        for (int d = 1; d < 64; d <<= 1) {
          unsigned int y = __shfl_up(x, d);
          if (lane >= d) x += y;
        }
        unsigned int excl = x - c;
        unsigned int S = carry + excl;
        bool hit = (S < r) && (r <= S + c);
        ull bal = __ballot(hit ? 1 : 0);
        if (bal != 0ull) {
          int hl = __ffsll((long long)bal) - 1;
          unsigned int Sf = __shfl(S, hl);
          unsigned int bf = __shfl((unsigned int)bin, hl);
          if (lane == 0) { sh_digit = bf; sh_r = r - Sf; }
          break;
        }
        carry += __shfl(x, 63);
      }
    }
    __syncthreads();
    prefix |= ((ull)sh_digit << shift);
    r = sh_r;
    __syncthreads();
  }
  const ull T = prefix;

  if (tid == 0) scnt = 0u;
  for (int i = tid; i < CAP; i += NT) { skey[i] = 0ull; sidx[i] = 0xFFFFFFFFu; }
  __syncthreads();
  #pragma unroll
  for (int q = 0; q < RQ; ++q) {
    const int i = tid + q * NT;
    if (i < NN) {
      ull k = rkey[q];
      if (k != 0ull && k >= T) {
        unsigned int pos = atomicAdd(&scnt, 1u);
        if (pos < CAP) { skey[pos] = k; sidx[pos] = (unsigned int)i; }
      }
    }
  }
  __syncthreads();

  for (unsigned int k2 = 2; k2 <= CAP; k2 <<= 1) {
    for (unsigned int j = k2 >> 1; j > 0; j >>= 1) {
      for (int i = tid; i < CAP; i += NT) {
        int ixj = i ^ (int)j;
        if (ixj > i) {
          bool up = ((i & k2) == 0);
          ull ka = skey[i], kb = skey[ixj];
          unsigned int ia = sidx[i], ib = sidx[ixj];
          bool a_after_b = (ka < kb) || (ka == kb && ia > ib);
          if (a_after_b == up) {
            skey[i] = kb; skey[ixj] = ka;
            sidx[i] = ib; sidx[ixj] = ia;
          }
        }
      }
      __syncthreads();
    }
  }

  const ull mykey = skey[tid];
  const unsigned int myidx = sidx[tid];
  double dX0 = 0.0, dY0 = 0.0, dX1 = 0.0, dY1 = 0.0, dAR = 0.0;
  {
    float v = -1.0f;
    if (mykey != 0ull) {
      decode_box_d(p_loc + ((size_t)b * NN + myidx) * 4,
                   anchors + (size_t)myidx * 4, dX0, dY0, dX1, dY1, dAR);
      double s = __longlong_as_double(
          (long long)(0x3FE0000000000000ull | (mykey - 1ull)));
      v = (float)s;
    }
    fb0[tid] = (float)dX0; fb1[tid] = (float)dY0;
    fb2[tid] = (float)dX1; fb3[tid] = (float)dY1;
    farr[tid] = (float)dAR;
    svalf[tid] = v;
  }
  if (tid < 16) supShared[tid] = 0ull;
  if (tid < 32) keepm[tid] = 0u;
  __syncthreads();

  const float cj0 = fb0[tid], cj1 = fb1[tid], cj2 = fb2[tid], cj3 = fb3[tid];
  const float caj = farr[tid];
  ull supw = 0ull;

  for (int c = 0; c < 32; ++c) {
    for (int rr = 0; rr < 32; ++rr) {
      const int i = c * 32 + rr;
      const bool rowDead =
          (svalf[i] < 0.0f) ||
          (((supShared[i >> 6] >> (i & 63)) & 1ull) != 0ull);
      if (rowDead) continue;
      float bi0 = fb0[i], bi1 = fb1[i], bi2 = fb2[i], bi3 = fb3[i];
      float ai = farr[i];
      float lt0 = fmaxf(bi0, cj0), lt1 = fmaxf(bi1, cj1);
      float q0 = fminf(bi2, cj2), q1 = fminf(bi3, cj3);
      float w0 = fmaxf(q0 - lt0, 0.0f), w1 = fmaxf(q1 - lt1, 0.0f);
      float inter = w0 * w1;
      float den = ((ai + caj) - inter) + 1e-9f;
      float d = inter - 0.3f * den;
      bool bit = d > 0.0f;
      bool unc = fabsf(d) <= den * 1e-3f;
      if (__builtin_expect((bool)__ballot(unc ? 1 : 0), 0)) {
        if (unc) {
          const unsigned int ridx = sidx[i];
          double rX0, rY0, rX1, rY1, rAR;
          decode_box_d(p_loc + ((size_t)b * NN + ridx) * 4,
                       anchors + (size_t)ridx * 4, rX0, rY0, rX1, rY1, rAR);
          bit = iou_gt_d(rX0, rY0, rX1, rY1, rAR, dX0, dY0, dX1, dY1, dAR);
        }
      }
      bit = bit && (tid > i);
      ull m = __ballot(bit ? 1 : 0);
      if (lane == 0) chunkmask[rr][wave] = m;
    }
    __syncthreads();
    if (wave == 0) {
      unsigned int km = 0u;
      for (int rr = 0; rr < 32; ++rr) {
        const int i = c * 32 + rr;
        ull sc = __shfl(supw, i >> 6);
        bool keep = (svalf[i] >= 0.0f) && (((sc >> (i & 63)) & 1ull) == 0ull);
        if (keep) {
          km |= (1u << rr);
          if (lane < 16) supw |= chunkmask[rr][lane];
        }
      }
      if (lane == 0) keepm[c] = km;
      if (lane < 16) supShared[lane] = supw;
    }
    __syncthreads();
  }

  {
    const bool keep = ((keepm[tid >> 5] >> (tid & 31)) & 1u) != 0u;
    float* op = out + ((size_t)b * KK + tid) * 15;
    if (keep) {
      op[0] = fb0[tid]; op[1] = fb1[tid]; op[2] = fb2[tid]; op[3] = fb3[tid];
      const float* pp = p_landms + ((size_t)b * NN + myidx) * 10;
      const float* ap = anchors + (size_t)myidx * 4;
      double a0 = (double)ap[0], a1 = (double)ap[1];
      double a2 = (double)ap[2], a3 = (double)ap[3];
      #pragma unroll
      for (int q = 0; q < 5; ++q) {
        double px = (double)pp[2 * q], py = (double)pp[2 * q + 1];
        op[4 + 2 * q]     = (float)(a0 + (px * 0.1) * a2);
        op[4 + 2 * q + 1] = (float)(a1 + (py * 0.1) * a3);
      }
      op[14] = svalf[tid];
    } else {
      #pragma unroll
      for (int q = 0; q < 15; ++q) op[q] = 0.0f;
    }
  }
}

extern "C" void kernel_launch(void* const* d_in, const int* in_sizes, int n_in,
                              void* d_out, int out_size, void* d_ws, size_t ws_size,
                              hipStream_t stream) {
  const float* p_loc    = (const float*)d_in[0];
  const float* p_conf   = (const float*)d_in[1];
  const float* p_landms = (const float*)d_in[2];
  const float* anchors  = (const float*)d_in[3];
  float* out = (float*)d_out;
  (void)in_sizes; (void)n_in; (void)out_size;

  // Workspace layout (keys live in sort registers):
  const size_t off_sidx = 0;
  const size_t off_fbox = off_sidx + (size_t)NB * KK * 4;          //   256 KB
  const size_t off_sval = off_fbox + (size_t)NB * 5 * KK * 4;      // +1280 KB
  const size_t off_mask = off_sval + (size_t)NB * KK * 4;          //  +256 KB
  const size_t mask_bytes = (size_t)NB * KK * 16 * sizeof(ull);    //  8192 KB
  const size_t total = off_mask + mask_bytes;                      // ~10.0 MB

  char* ws = (char*)d_ws;

  if (ws_size >= total) {
    unsigned int* sidx_s = (unsigned int*)(ws + off_sidx);
    float* fbox = (float*)(ws + off_fbox);
    float* sval = (float*)(ws + off_sval);
    ull* maskg = (ull*)(ws + off_mask);

    hipLaunchKernelGGL(sort_kernel, dim3(NB), dim3(NT), 0, stream,
                       p_loc, p_conf, anchors, sidx_s, fbox, sval);
    hipLaunchKernelGGL(pair_kernel, dim3(NB, 34), dim3(256), 0, stream,
                       p_loc, anchors, sidx_s, fbox, sval, maskg);
    hipLaunchKernelGGL(resolve_kernel, dim3(NB), dim3(NT), 0, stream,
                       p_landms, anchors, sidx_s, fbox, sval, maskg, out);
  } else {
    hipLaunchKernelGGL(fallback_kernel, dim3(NB), dim3(NT), 0, stream,
                       p_loc, p_conf, p_landms, anchors, (const ull*)nullptr,
                       out);
  }
}

// Round 14
// 197.340 us; speedup vs baseline: 1.5691x; 1.0166x over previous
//
#include <hip/hip_runtime.h>
#include <cmath>

#define NB 64
#define NN 16800
#define KK 1024
#define NT 1024
#define CAP 2048
#define RQ 17  // ceil(NN/NT)

typedef unsigned long long ull;

// Key (R13): fp32 conf bits, order-isomorphic to the double-sigmoid key
// (sigmoid strictly monotone; ties iff bit-equal cf; s>=0.5 <=> cf>=0
// exactly in both precisions). key = (bits&0x7FFFFFFF)+1 for cf>=0, else 0.
__device__ __forceinline__ unsigned int score_key_f(float cf) {
  if (!(cf >= 0.0f)) return 0u;
  return (__float_as_uint(cf) & 0x7FFFFFFFu) + 1u;
}

// Monotone exact bin: floor(cf*1024) clamped (power-of-2 scale, no rounding).
__device__ __forceinline__ unsigned int bin_of_key(unsigned int key) {
  float cf = __uint_as_float(key - 1u);  // key>=1: magnitude bits of cf
  unsigned int bi = (unsigned int)(int)(cf * 1024.0f);
  return bi > 4095u ? 4095u : bi;
}

// Legacy double key (fallback_kernel only).
__device__ __forceinline__ ull score_key_d(float cf) {
  double s = 1.0 / (1.0 + exp(-(double)cf));
  if (!(s >= 0.5)) return 0ull;
  return ((ull)__double_as_longlong(s) & 0xFFFFFFFFFFFFFull) + 1ull;
}

// Shared double box decode (contract off => one codegen, numpy op order).
__device__ __forceinline__ void decode_box_d(const float* lp, const float* ap,
                                             double& X0, double& Y0,
                                             double& X1, double& Y1,
                                             double& AR) {
#pragma clang fp contract(off)
  double l0 = (double)lp[0], l1 = (double)lp[1];
  double l2 = (double)lp[2], l3 = (double)lp[3];
  double a0 = (double)ap[0], a1 = (double)ap[1];
  double a2 = (double)ap[2], a3 = (double)ap[3];
  double xy0 = a0 + (l0 * 0.1) * a2;
  double xy1 = a1 + (l1 * 0.1) * a3;
  double w = a2 * exp(l2 * 0.2);
  double h = a3 * exp(l3 * 0.2);
  X0 = xy0 - w * 0.5; Y0 = xy1 - h * 0.5;
  X1 = xy0 + w * 0.5; Y1 = xy1 + h * 0.5;
  AR = fmax(X1 - X0, 0.0) * fmax(Y1 - Y0, 0.0);
}

__device__ __forceinline__ bool iou_gt_d(double i0, double i1, double i2,
                                         double i3, double ia, double j0,
                                         double j1, double j2, double j3,
                                         double ja) {
#pragma clang fp contract(off)
  double lt0 = fmax(i0, j0), lt1 = fmax(i1, j1);
  double rb0 = fmin(i2, j2), rb1 = fmin(i3, j3);
  double w0 = fmax(rb0 - lt0, 0.0), w1 = fmax(rb1 - lt1, 0.0);
  double inter = w0 * w1;
  double den = ((ia + ja) - inter) + 1e-9;  // ref op order
  return (inter / den) > 0.3;
}

// 64-bit readlane: 2x v_readlane_b32 -> SGPR pair (fast, no LDS pipe)
__device__ __forceinline__ ull readlane64(ull v, int l) {
  unsigned int lo = __builtin_amdgcn_readlane((unsigned int)v, l);
  unsigned int hi = __builtin_amdgcn_readlane((unsigned int)(v >> 32), l);
  return ((ull)hi << 32) | (ull)lo;
}

// ---- K2: per-image exact counting sort, fp32-bit keys in-register ---------
__global__ __launch_bounds__(1024, 1) void sort_kernel(
    const float* __restrict__ p_loc, const float* __restrict__ p_conf,
    const float* __restrict__ anchors, unsigned int* __restrict__ sidx_s,
    float* __restrict__ fbox, float* __restrict__ sval) {
  const int b = blockIdx.x;
  const int tid = threadIdx.x;
  const int lane = tid & 63;
  const int wave = tid >> 6;

  __shared__ unsigned int skey[CAP];   // 8 KB
  __shared__ unsigned int sidx[CAP];   // 8 KB
  __shared__ unsigned int hist[4096];  // 16 KB ([0..256) reused by fallback)
  __shared__ unsigned int base[4096];  // 16 KB
  __shared__ unsigned int totals[64], chcarry[64];
  __shared__ unsigned int sh_found, sh_binT, sh_cB;
  __shared__ unsigned int scnt, sh_digit, sh_r, sh_c;

  const float* conf = p_conf + (size_t)b * NN;

  // ---------- keys in registers ----------
  unsigned int rkey[RQ];
  #pragma unroll
  for (int q = 0; q < RQ; ++q) {
    const int i = tid + q * NT;
    rkey[q] = (i < NN) ? score_key_f(conf[i]) : 0u;
  }

  // ---------- FAST PATH: 12-bit counting sort ----------
  for (int i = tid; i < 4096; i += NT) hist[i] = 0u;
  if (tid == 0) sh_found = 0u;
  __syncthreads();
  #pragma unroll
  for (int q = 0; q < RQ; ++q) {
    unsigned int k = rkey[q];
    if (k != 0u) atomicAdd(&hist[bin_of_key(k)], 1u);
  }
  __syncthreads();
  // pass1: within-chunk inclusive scans from the high end (lane0 = high bin)
  for (int chunk = wave; chunk < 64; chunk += 16) {
    const int bin = chunk * 64 + (63 - lane);
    unsigned int c0 = hist[bin];
    unsigned int x = c0;
    #pragma unroll
    for (int d = 1; d < 64; d <<= 1) {
      unsigned int y = __shfl_up(x, d);
      if (lane >= d) x += y;
    }
    base[bin] = x;  // inclusive count of bins >= bin within chunk
    if (lane == 63) totals[chunk] = x;
  }
  __syncthreads();
  // chunk-level exclusive suffix (sum of strictly higher chunks)
  if (wave == 0) {
    const int chunk = 63 - lane;  // lane0 = highest chunk
    unsigned int t0 = totals[chunk];
    unsigned int x = t0;
    #pragma unroll
    for (int d = 1; d < 64; d <<= 1) {
      unsigned int y = __shfl_up(x, d);
      if (lane >= d) x += y;
    }
    chcarry[chunk] = x - t0;
  }
  __syncthreads();
  // pass2: finalize exact base ranks, detect the rank-1024 crossing bin
  for (int chunk = wave; chunk < 64; chunk += 16) {
    const int bin = chunk * 64 + (63 - lane);
    unsigned int c0 = hist[bin];
    unsigned int S = chcarry[chunk] + base[bin] - c0;  // strictly-higher total
    base[bin] = S;
    if (S < (unsigned)KK && (unsigned)KK <= S + c0) {
      sh_found = 1u; sh_binT = (unsigned int)bin; sh_cB = c0;
    }
  }
  __syncthreads();
  const bool fastOK = (sh_found != 0u) && (sh_cB <= 64u);
  const unsigned int binT = sh_binT;

  if (fastOK) {
    for (int i = tid; i < KK + 64; i += NT) { skey[i] = 0u; sidx[i] = 0xFFFFFFFFu; }
    __syncthreads();
    // scatter: candidates in bins >= binT land at exact rank + arrival offset
    #pragma unroll
    for (int q = 0; q < RQ; ++q) {
      const int i = tid + q * NT;
      unsigned int k = rkey[q];
      if (k != 0u) {
        unsigned int bin = bin_of_key(k);
        if (bin >= binT) {
          unsigned int pos = atomicAdd(&base[bin], 1u);
          if (pos < (unsigned)(KK + 64)) { skey[pos] = k; sidx[pos] = (unsigned int)i; }
        }
      }
    }
    __syncthreads();
    // in-bin cleanup: sort each bin slice by (key desc, idx asc); disjoint
    for (int bin = (int)binT + tid; bin < 4096; bin += NT) {
      unsigned int cnt = hist[bin];
      if (cnt >= 2u) {
        int hi2 = (int)base[bin];       // orig + cnt after scatter
        int lo2 = hi2 - (int)cnt;
        for (int m2 = lo2 + 1; m2 < hi2; ++m2) {
          unsigned int kx = skey[m2]; unsigned int ix = sidx[m2];
          int n2 = m2;
          while (n2 > lo2) {
            unsigned int kp = skey[n2 - 1]; unsigned int ip = sidx[n2 - 1];
            bool after = (kp < kx) || (kp == kx && ip > ix);
            if (!after) break;
            skey[n2] = kp; sidx[n2] = ip; --n2;
          }
          skey[n2] = kx; sidx[n2] = ix;
        }
      }
    }
    __syncthreads();
  } else {
    // ---------- FALLBACK: radix-select (32-bit) + bitonic-2048 ----------
    unsigned int r = KK;
    unsigned int prefix = 0u, T = 0u;
    for (int pass = 0; pass < 4; ++pass) {
      const int shift = 24 - pass * 8;
      if (tid < 256) hist[tid] = 0u;
      __syncthreads();
      const unsigned int pm = pass ? ~((1u << (shift + 8)) - 1u) : 0u;
      #pragma unroll
      for (int q = 0; q < RQ; ++q) {
        unsigned int k = rkey[q];
        if (k != 0u && (k & pm) == prefix)
          atomicAdd(&hist[(k >> shift) & 255u], 1u);
      }
      __syncthreads();
      if (wave == 0) {
        if (lane == 0) { sh_digit = 0u; sh_r = r; sh_c = 0u; }
        unsigned int carry = 0;
        for (int chunk = 3; chunk >= 0; --chunk) {
          const int bin = chunk * 64 + (63 - lane);
          unsigned int c = hist[bin];
          unsigned int x = c;
          #pragma unroll
          for (int d = 1; d < 64; d <<= 1) {
            unsigned int y = __shfl_up(x, d);
            if (lane >= d) x += y;
          }
          unsigned int excl = x - c;
          unsigned int S = carry + excl;
          bool hit = (S < r) && (r <= S + c);
          ull bal = __ballot(hit ? 1 : 0);
          if (bal != 0ull) {
            int hl = __ffsll((long long)bal) - 1;
            unsigned int Sf = __shfl(S, hl);
            unsigned int bf = __shfl((unsigned int)bin, hl);
            unsigned int cf2 = __shfl(c, hl);
            if (lane == 0) { sh_digit = bf; sh_r = r - Sf; sh_c = cf2; }
            break;
          }
          carry += __shfl(x, 63);
        }
      }
      __syncthreads();
      prefix |= (sh_digit << shift);
      r = sh_r;
      const unsigned int cntge = (KK - r) + sh_c;
      if (cntge <= CAP || pass == 3) { T = prefix; break; }
    }

    if (tid == 0) scnt = 0u;
    for (int i = tid; i < CAP; i += NT) { skey[i] = 0u; sidx[i] = 0xFFFFFFFFu; }
    __syncthreads();
    #pragma unroll
    for (int q = 0; q < RQ; ++q) {
      const int i = tid + q * NT;
      unsigned int k = rkey[q];
      if (k != 0u && k >= T) {
        unsigned int pos = atomicAdd(&scnt, 1u);
        if (pos < CAP) { skey[pos] = k; sidx[pos] = (unsigned int)i; }
      }
    }
    __syncthreads();

    for (unsigned int k2 = 2; k2 <= CAP; k2 <<= 1) {
      for (unsigned int j = k2 >> 1; j > 0; j >>= 1) {
        for (int i = tid; i < CAP; i += NT) {
          int ixj = i ^ (int)j;
          if (ixj > i) {
            bool up = ((i & k2) == 0);
            unsigned int ka = skey[i], kbv = skey[ixj];
            unsigned int ia = sidx[i], ib = sidx[ixj];
            bool a_after_b = (ka < kbv) || (ka == kbv && ia > ib);
            if (a_after_b == up) {
              skey[i] = kbv; skey[ixj] = ka;
              sidx[i] = ib; sidx[ixj] = ia;
            }
          }
        }
        __syncthreads();
      }
    }
  }

  // ---------- decode top-K boxes in double, emit fp32 + idx + score --------
  const unsigned int mykey = skey[tid];
  const unsigned int myidx = sidx[tid];
  double X0 = 0.0, Y0 = 0.0, X1 = 0.0, Y1 = 0.0, AR = 0.0;
  float v = -1.0f;
  if (mykey != 0u) {
    decode_box_d(p_loc + ((size_t)b * NN + myidx) * 4,
                 anchors + (size_t)myidx * 4, X0, Y0, X1, Y1, AR);
    double s = 1.0 / (1.0 + exp(-(double)conf[myidx]));
    v = (float)s;
  }
  sidx_s[(size_t)b * KK + tid] = myidx;
  float* fb = fbox + (size_t)b * 5 * KK;
  fb[0 * KK + tid] = (float)X0; fb[1 * KK + tid] = (float)Y0;
  fb[2 * KK + tid] = (float)X1; fb[3 * KK + tid] = (float)Y1;
  fb[4 * KK + tid] = (float)AR;
  sval[(size_t)b * KK + tid] = v;
}

// ---- K3: triangle IoU bitmask, one (rowgroup,colgroup) task per wave ------
// grid = (64 img, 34); block = 256 (4 waves). Final form (best measured:
// 49.2-49.5 us): LDS same-address row broadcast, 8-row register chunks.
// Floor is ballot/exec-mask machinery (4 restructures converged to 49-51).
__global__ __launch_bounds__(256) void pair_kernel(
    const float* __restrict__ p_loc, const float* __restrict__ anchors,
    const unsigned int* __restrict__ sidx_s, const float* __restrict__ fbox,
    const float* __restrict__ sval, ull* __restrict__ maskg) {
  const int img = blockIdx.x;
  const int wave = threadIdx.x >> 6;
  const int lane = threadIdx.x & 63;
  const int t = blockIdx.y * 4 + wave;  // 0..135

  int rg = 0, rem = t;
  while (rem >= 16 - rg) { rem -= 16 - rg; ++rg; }
  const int cg = rg + rem;

  const int rgs = __builtin_amdgcn_readfirstlane(rg);  // uniform rg

  __shared__ float rowbuf[4][64][8];  // 8 KB; [wave] slices, wave-coherent

  const float* fb = fbox + (size_t)img * 5 * KK;
  const int irow = rgs * 64 + lane;
  const int jcol = cg * 64 + lane;

  // one-time stage: lane l loads row (rgs*64+l)'s box, writes its LDS row
  {
    const float v0 = fb[0 * KK + irow], v1 = fb[1 * KK + irow];
    const float v2 = fb[2 * KK + irow], v3 = fb[3 * KK + irow];
    const float va = fb[4 * KK + irow];
    float4* dst = reinterpret_cast<float4*>(&rowbuf[wave][lane][0]);
    *dst = make_float4(v0, v1, v2, v3);
    rowbuf[wave][lane][4] = va;
  }

  const unsigned int ri = sidx_s[(size_t)img * KK + irow];  // rare path only

  const float cj0 = fb[0 * KK + jcol], cj1 = fb[1 * KK + jcol];
  const float cj2 = fb[2 * KK + jcol], cj3 = fb[3 * KK + jcol];
  const float caj = fb[4 * KK + jcol];
  const unsigned int cidx = sidx_s[(size_t)img * KK + jcol];

  unsigned int wlo = 0u, whi = 0u;  // lane rr holds mask word for row rr

  for (int rc = 0; rc < 64; rc += 8) {
    // ---- chunk prefetch: 16 independent LDS broadcast reads ----
    float b0r[8], b1r[8], b2r[8], b3r[8], bar[8];
    #pragma unroll
    for (int u = 0; u < 8; ++u) {
      const float4 bq =
          *reinterpret_cast<const float4*>(&rowbuf[wave][rc + u][0]);
      b0r[u] = bq.x; b1r[u] = bq.y; b2r[u] = bq.z; b3r[u] = bq.w;
      bar[u] = rowbuf[wave][rc + u][4];
    }
    // ---- 8 row bodies from registers ----
    #pragma unroll
    for (int u = 0; u < 8; ++u) {
      const int rr = rc + u;
      const float bi0 = b0r[u], bi1 = b1r[u];
      const float bi2 = b2r[u], bi3 = b3r[u];
      const float ai = bar[u];
      float lt0 = fmaxf(bi0, cj0), lt1 = fmaxf(bi1, cj1);
      float q0 = fminf(bi2, cj2), q1 = fminf(bi3, cj3);
      float w0 = fmaxf(q0 - lt0, 0.0f), w1 = fmaxf(q1 - lt1, 0.0f);
      float inter = w0 * w1;
      float den = ((ai + caj) - inter) + 1e-9f;
      float d = inter - 0.3f * den;     // sign(d) = sign(iou - 0.3)
      bool bit = d > 0.0f;
      bool unc = fabsf(d) <= den * 1e-3f;  // fp32 iou err ~1e-5 << 1e-3
      if (__builtin_expect((bool)__ballot(unc ? 1 : 0), 0)) {
        const unsigned int rbi = __builtin_amdgcn_readlane(ri, rr);
        if (unc) {
          double rX0, rY0, rX1, rY1, rAR, qX0, qY0, qX1, qY1, qAR;
          decode_box_d(p_loc + ((size_t)img * NN + rbi) * 4,
                       anchors + (size_t)rbi * 4, rX0, rY0, rX1, rY1, rAR);
          decode_box_d(p_loc + ((size_t)img * NN + cidx) * 4,
                       anchors + (size_t)cidx * 4, qX0, qY0, qX1, qY1, qAR);
          bit = iou_gt_d(rX0, rY0, rX1, rY1, rAR, qX0, qY0, qX1, qY1, qAR);
        }
      }
      bit = bit && (jcol > rgs * 64 + rr);  // j > i
      ull m = __ballot(bit ? 1 : 0);
      const bool mine = (lane == rr);
      wlo = mine ? (unsigned int)m : wlo;
      whi = mine ? (unsigned int)(m >> 32) : whi;
    }
  }

  maskg[((size_t)img * KK + (size_t)rgs * 64 + lane) * 16 + cg] =
      ((ull)whi << 32) | (ull)wlo;
}

// ---- K4 (R24): resolve without the staging skeleton -----------------------
// 256 threads/block, one block/image. This is the R17 resolve phase
// (correctness-verified in the R17 run: passed, same absmax) lifted to a
// standalone kernel: diag words gathered from global with one-group-ahead
// prefetch feeding the R14 pure-SALU serial scan; cross-word suppression
// ORs as km-predicated global gathers + LDS atomicOr (16 threads/word,
// 4 rows each); 2 barriers/group. Removes the 1024-thread 8-stage LDS
// bulk-staging (loaded 128KB/image; algorithm touches only ~45KB).
// Decision-identical by the R14 argument: sup[w] only read at group w
// start; word-g handled exactly by the scan's curw.
__global__ __launch_bounds__(256) void resolve_kernel(
    const float* __restrict__ p_landms, const float* __restrict__ anchors,
    const unsigned int* __restrict__ sidx_s, const float* __restrict__ fbox,
    const float* __restrict__ sval, const ull* __restrict__ maskg,
    float* __restrict__ out) {
  const int img = blockIdx.x, tid = threadIdx.x, lane = tid & 63,
            wave = tid >> 6;
  __shared__ ull vmw[16], supLDS[16], keepw16[16], kmsh;
  const ull* mg = maskg + (size_t)img * KK * 16;

  #pragma unroll
  for (int k = 0; k < 4; ++k) {  // validity ballots: wave w -> groups 4w..4w+3
    const int g = wave * 4 + k;
    const float v = sval[(size_t)img * KK + g * 64 + lane];
    const ull vm = __ballot(v >= 0.0f);
    if (lane == 0) vmw[g] = vm;
  }
  if (tid < 16) supLDS[tid] = 0ull;
  __syncthreads();

  ull diag_next = 0ull;
  if (wave == 0) diag_next = mg[(size_t)lane * 16 + 0];  // group 0 diag words
  for (int g = 0; g < 16; ++g) {
    if (wave == 0) {
      const ull diagw = diag_next;
      if (g < 15)
        diag_next = mg[(size_t)((g + 1) * 64 + lane) * 16 + (g + 1)];
      const ull vm = vmw[g];
      ull curw = supLDS[g];
      ull km = 0ull;
      #pragma unroll 8
      for (int rr = 0; rr < 64; ++rr) {
        const ull mw = readlane64(diagw, rr);  // independent of chain
        const ull bitm = 1ull << rr;
        const ull keepbit = (vm & ~curw) & bitm;
        km |= keepbit;
        curw |= (keepbit != 0ull) ? mw : 0ull;
      }
      if (lane == 0) { keepw16[g] = km; kmsh = km; }
    }
    __syncthreads();
    if (g < 15) {
      // deferred cross-word OR: 16 threads/word, 4 rows each, km-predicated
      const ull km = kmsh;
      const int w = tid >> 4, sub = tid & 15;
      if (w > g) {
        ull acc = 0ull;
        #pragma unroll
        for (int r2 = 0; r2 < 4; ++r2) {
          const int rr = sub * 4 + r2;
          if ((km >> rr) & 1ull)
            acc |= mg[(size_t)(g * 64 + rr) * 16 + w];
        }
        if (acc != 0ull) atomicOr(&supLDS[w], acc);
      }
    }
    __syncthreads();
  }

  // ---- output epilogue (256 threads x 4 rows) -----------------------------
  const float* fb = fbox + (size_t)img * 5 * KK;
  #pragma unroll
  for (int k = 0; k < 4; ++k) {
    const int row = tid + k * 256;
    const bool keep = ((keepw16[row >> 6] >> (row & 63)) & 1ull) != 0ull;
    float* op = out + ((size_t)img * KK + row) * 15;
    if (keep) {
      op[0] = fb[0 * KK + row]; op[1] = fb[1 * KK + row];
      op[2] = fb[2 * KK + row]; op[3] = fb[3 * KK + row];
      const unsigned int myidx = sidx_s[(size_t)img * KK + row];
      const float* pp = p_landms + ((size_t)img * NN + myidx) * 10;
      const float* ap = anchors + (size_t)myidx * 4;
      double a0 = (double)ap[0], a1 = (double)ap[1];
      double a2 = (double)ap[2], a3 = (double)ap[3];
      #pragma unroll
      for (int q = 0; q < 5; ++q) {
        double px = (double)pp[2 * q], py = (double)pp[2 * q + 1];
        op[4 + 2 * q]     = (float)(a0 + (px * 0.1) * a2);
        op[4 + 2 * q + 1] = (float)(a1 + (py * 0.1) * a3);
      }
      op[14] = sval[(size_t)img * KK + row];
    } else {
      #pragma unroll
      for (int q = 0; q < 15; ++q) op[q] = 0.0f;
    }
  }
}

// ---- Fallback: R4 monolithic (passed; used only if ws too small) ----------
__global__ __launch_bounds__(1024, 1) void fallback_kernel(
    const float* __restrict__ p_loc, const float* __restrict__ p_conf,
    const float* __restrict__ p_landms, const float* __restrict__ anchors,
    const ull* __restrict__ gkeys, float* __restrict__ out) {
  const int b = blockIdx.x;
  const int tid = threadIdx.x;
  const int lane = tid & 63;
  const int wave = tid >> 6;

  __shared__ ull skey[CAP];
  __shared__ unsigned int sidx[CAP];
  __shared__ float fb0[KK], fb1[KK], fb2[KK], fb3[KK], farr[KK];
  __shared__ float svalf[KK];
  __shared__ ull chunkmask[32][16];
  __shared__ unsigned int keepm[32];
  __shared__ ull supShared[16];
  __shared__ unsigned int hist[256];
  __shared__ unsigned int scnt, sh_digit, sh_r;

  unsigned long long rkey[RQ];
  if (gkeys != nullptr) {
    const ull* kb = gkeys + (size_t)b * NN;
    #pragma unroll
    for (int q = 0; q < RQ; ++q) {
      const int i = tid + q * NT;
      rkey[q] = (i < NN) ? kb[i] : 0ull;
    }
  } else {
    const float* conf = p_conf + (size_t)b * NN;
    #pragma unroll
    for (int q = 0; q < RQ; ++q) {
      const int i = tid + q * NT;
      rkey[q] = (i < NN) ? score_key_d(conf[i]) : 0ull;
    }
  }

  unsigned int r = KK;
  ull prefix = 0ull;
  for (int pass = 0; pass < 7; ++pass) {
    const int shift = 48 - pass * 8;
    if (tid < 256) hist[tid] = 0u;
    __syncthreads();
    const ull pm = (pass == 0) ? 0ull : ~((1ull << (shift + 8)) - 1ull);
    #pragma unroll
    for (int q = 0; q < RQ; ++q) {
      const int i = tid + q * NT;
      if (i < NN) {
        ull k = rkey[q];
        if (k != 0ull && (k & pm) == prefix)
          atomicAdd(&hist[(unsigned int)(k >> shift) & 255u], 1u);
      }
    }
    __syncthreads();
    if (wave == 0) {
      if (lane == 0) { sh_digit = 0u; sh_r = r; }
      unsigned int carry = 0;
      for (int chunk = 3; chunk >= 0; --chunk) {
        const int bin = chunk * 64 + (63 - lane);
        unsigned int c = hist[bin];
        unsigned int x = c;
        #pragma unroll
        for (int d = 1; d < 64; d <<= 1) {
          unsigned int y = __shfl_up(x, d);
          if (lane >= d) x += y;
        }
        unsigned int excl = x - c;
        unsigned int S = carry + excl;
        bool hit = (S < r) && (r <= S + c);
        ull bal = __ballot(hit ? 1 : 0);
        if (bal != 0ull) {
          int hl = __ffsll((long long)bal) - 1;
          unsigned int Sf = __shfl(S, hl);
          unsigned int bf = __shfl((unsigned int)bin, hl);
          if (lane == 0) { sh_digit = bf; sh_r = r - Sf; }
          break;
        }
        carry += __shfl(x, 63);
      }
    }
    __syncthreads();
    prefix |= ((ull)sh_digit << shift);
    r = sh_r;
    __syncthreads();
  }
  const ull T = prefix;

  if (tid == 0) scnt = 0u;
  for (int i = tid; i < CAP; i += NT) { skey[i] = 0ull; sidx[i] = 0xFFFFFFFFu; }
  __syncthreads();
  #pragma unroll
  for (int q = 0; q < RQ; ++q) {
    const int i = tid + q * NT;
    if (i < NN) {
      ull k = rkey[q];
      if (k != 0ull && k >= T) {
        unsigned int pos = atomicAdd(&scnt, 1u);
        if (pos < CAP) { skey[pos] = k; sidx[pos] = (unsigned int)i; }
      }
    }
  }
  __syncthreads();

  for (unsigned int k2 = 2; k2 <= CAP; k2 <<= 1) {
    for (unsigned int j = k2 >> 1; j > 0; j >>= 1) {
      for (int i = tid; i < CAP; i += NT) {
        int ixj = i ^ (int)j;
        if (ixj > i) {
          bool up = ((i & k2) == 0);
          ull ka = skey[i], kb = skey[ixj];
          unsigned int ia = sidx[i], ib = sidx[ixj];
          bool a_after_b = (ka < kb) || (ka == kb && ia > ib);
          if (a_after_b == up) {
            skey[i] = kb; skey[ixj] = ka;
            sidx[i] = ib; sidx[ixj] = ia;
          }
        }
      }
      __syncthreads();
    }
  }

  const ull mykey = skey[tid];
  const unsigned int myidx = sidx[tid];
  double dX0 = 0.0, dY0 = 0.0, dX1 = 0.0, dY1 = 0.0, dAR = 0.0;
  {
    float v = -1.0f;
    if (mykey != 0ull) {
      decode_box_d(p_loc + ((size_t)b * NN + myidx) * 4,
                   anchors + (size_t)myidx * 4, dX0, dY0, dX1, dY1, dAR);
      double s = __longlong_as_double(
          (long long)(0x3FE0000000000000ull | (mykey - 1ull)));
      v = (float)s;
    }
    fb0[tid] = (float)dX0; fb1[tid] = (float)dY0;
    fb2[tid] = (float)dX1; fb3[tid] = (float)dY1;
    farr[tid] = (float)dAR;
    svalf[tid] = v;
  }
  if (tid < 16) supShared[tid] = 0ull;
  if (tid < 32) keepm[tid] = 0u;
  __syncthreads();

  const float cj0 = fb0[tid], cj1 = fb1[tid], cj2 = fb2[tid], cj3 = fb3[tid];
  const float caj = farr[tid];
  ull supw = 0ull;

  for (int c = 0; c < 32; ++c) {
    for (int rr = 0; rr < 32; ++rr) {
      const int i = c * 32 + rr;
      const bool rowDead =
          (svalf[i] < 0.0f) ||
          (((supShared[i >> 6] >> (i & 63)) & 1ull) != 0ull);
      if (rowDead) continue;
      float bi0 = fb0[i], bi1 = fb1[i], bi2 = fb2[i], bi3 = fb3[i];
      float ai = farr[i];
      float lt0 = fmaxf(bi0, cj0), lt1 = fmaxf(bi1, cj1);
      float q0 = fminf(bi2, cj2), q1 = fminf(bi3, cj3);
      float w0 = fmaxf(q0 - lt0, 0.0f), w1 = fmaxf(q1 - lt1, 0.0f);
      float inter = w0 * w1;
      float den = ((ai + caj) - inter) + 1e-9f;
      float d = inter - 0.3f * den;
      bool bit = d > 0.0f;
      bool unc = fabsf(d) <= den * 1e-3f;
      if (__builtin_expect((bool)__ballot(unc ? 1 : 0), 0)) {
        if (unc) {
          const unsigned int ridx = sidx[i];
          double rX0, rY0, rX1, rY1, rAR;
          decode_box_d(p_loc + ((size_t)b * NN + ridx) * 4,
                       anchors + (size_t)ridx * 4, rX0, rY0, rX1, rY1, rAR);
          bit = iou_gt_d(rX0, rY0, rX1, rY1, rAR, dX0, dY0, dX1, dY1, dAR);
        }
      }
      bit = bit && (tid > i);
      ull m = __ballot(bit ? 1 : 0);
      if (lane == 0) chunkmask[rr][wave] = m;
    }
    __syncthreads();
    if (wave == 0) {
      unsigned int km = 0u;
      for (int rr = 0; rr < 32; ++rr) {
        const int i = c * 32 + rr;
        ull sc = __shfl(supw, i >> 6);
        bool keep = (svalf[i] >= 0.0f) && (((sc >> (i & 63)) & 1ull) == 0ull);
        if (keep) {
          km |= (1u << rr);
          if (lane < 16) supw |= chunkmask[rr][lane];
        }
      }
      if (lane == 0) keepm[c] = km;
      if (lane < 16) supShared[lane] = supw;
    }
    __syncthreads();
  }

  {
    const bool keep = ((keepm[tid >> 5] >> (tid & 31)) & 1u) != 0u;
    float* op = out + ((size_t)b * KK + tid) * 15;
    if (keep) {
      op[0] = fb0[tid]; op[1] = fb1[tid]; op[2] = fb2[tid]; op[3] = fb3[tid];
      const float* pp = p_landms + ((size_t)b * NN + myidx) * 10;
      const float* ap = anchors + (size_t)myidx * 4;
      double a0 = (double)ap[0], a1 = (double)ap[1];
      double a2 = (double)ap[2], a3 = (double)ap[3];
      #pragma unroll
      for (int q = 0; q < 5; ++q) {
        double px = (double)pp[2 * q], py = (double)pp[2 * q + 1];
        op[4 + 2 * q]     = (float)(a0 + (px * 0.1) * a2);
        op[4 + 2 * q + 1] = (float)(a1 + (py * 0.1) * a3);
      }
      op[14] = svalf[tid];
    } else {
      #pragma unroll
      for (int q = 0; q < 15; ++q) op[q] = 0.0f;
    }
  }
}

extern "C" void kernel_launch(void* const* d_in, const int* in_sizes, int n_in,
                              void* d_out, int out_size, void* d_ws, size_t ws_size,
                              hipStream_t stream) {
  const float* p_loc    = (const float*)d_in[0];
  const float* p_conf   = (const float*)d_in[1];
  const float* p_landms = (const float*)d_in[2];
  const float* anchors  = (const float*)d_in[3];
  float* out = (float*)d_out;
  (void)in_sizes; (void)n_in; (void)out_size;

  // Workspace layout (keys live in sort registers):
  const size_t off_sidx = 0;
  const size_t off_fbox = off_sidx + (size_t)NB * KK * 4;          //   256 KB
  const size_t off_sval = off_fbox + (size_t)NB * 5 * KK * 4;      // +1280 KB
  const size_t off_mask = off_sval + (size_t)NB * KK * 4;          //  +256 KB
  const size_t mask_bytes = (size_t)NB * KK * 16 * sizeof(ull);    //  8192 KB
  const size_t total = off_mask + mask_bytes;                      // ~10.0 MB

  char* ws = (char*)d_ws;

  if (ws_size >= total) {
    unsigned int* sidx_s = (unsigned int*)(ws + off_sidx);
    float* fbox = (float*)(ws + off_fbox);
    float* sval = (float*)(ws + off_sval);
    ull* maskg = (ull*)(ws + off_mask);

    hipLaunchKernelGGL(sort_kernel, dim3(NB), dim3(NT), 0, stream,
                       p_loc, p_conf, anchors, sidx_s, fbox, sval);
    hipLaunchKernelGGL(pair_kernel, dim3(NB, 34), dim3(256), 0, stream,
                       p_loc, anchors, sidx_s, fbox, sval, maskg);
    hipLaunchKernelGGL(resolve_kernel, dim3(NB), dim3(256), 0, stream,
                       p_landms, anchors, sidx_s, fbox, sval, maskg, out);
  } else {
    hipLaunchKernelGGL(fallback_kernel, dim3(NB), dim3(NT), 0, stream,
                       p_loc, p_conf, p_landms, anchors, (const ull*)nullptr,
                       out);
  }
}